// Round 14
// baseline (93.485 us; speedup 1.0000x reference)
//
#include <hip/hip_runtime.h>
#include <hip/hip_cooperative_groups.h>
#include <math.h>

namespace cgx = cooperative_groups;

#define POOLED 7
#define SCALE 0.0625f
#define C_ 256
#define H_ 56
#define W_ 56
#define S_ (H_ * W_)   // 3136
#define NCELL 49

typedef _Float16 f16x4 __attribute__((ext_vector_type(4)));
typedef _Float16 f16x8 __attribute__((ext_vector_type(8)));

__device__ __forceinline__ f16x8 max8h(f16x8 a, f16x8 b) {
    f16x8 r;
    #pragma unroll
    for (int i = 0; i < 8; ++i) r[i] = a[i] > b[i] ? a[i] : b[i];
    return r;
}

// ---------------- shared device bodies ----------------
__device__ __forceinline__ void nhwc_tile_body(
    const float* __restrict__ feat, _Float16* __restrict__ t,
    int v, int tid, float (*tile)[65])
{
    int b     = v / 196;
    int rem   = v % 196;
    int cbase = (rem / 49) * 64;
    int sbase = (rem % 49) * 64;
    const float* s0 = feat + (size_t)b * C_ * S_;
    _Float16*    d0 = t    + (size_t)b * S_ * C_;

    int si = tid & 15;          // s-quad
    int ci = tid >> 4;          // 0..15
    #pragma unroll
    for (int p = 0; p < 4; ++p) {
        int c = ci + 16 * p;
        float4 vv = *(const float4*)(s0 + (size_t)(cbase + c) * S_ + sbase + 4 * si);
        tile[4 * si + 0][c] = vv.x;
        tile[4 * si + 1][c] = vv.y;
        tile[4 * si + 2][c] = vv.z;
        tile[4 * si + 3][c] = vv.w;
    }
    __syncthreads();
    int cj = tid & 15;          // c-quad
    int sj = tid >> 4;          // 0..15
    #pragma unroll
    for (int p = 0; p < 4; ++p) {
        int s = sj + 16 * p;
        f16x4 pk;
        pk[0] = (_Float16)tile[s][4 * cj + 0];
        pk[1] = (_Float16)tile[s][4 * cj + 1];
        pk[2] = (_Float16)tile[s][4 * cj + 2];
        pk[3] = (_Float16)tile[s][4 * cj + 3];
        *(f16x4*)(d0 + (size_t)(sbase + s) * C_ + cbase + 4 * cj) = pk;
    }
    __syncthreads();
}

__device__ __forceinline__ void pool_unit_body(
    const _Float16* __restrict__ t, const float* __restrict__ rois,
    float* __restrict__ out, int u, int tid, float (*stage)[257])
{
    int swz  = (u & 7) * 416 + (u >> 3);   // bijective XCD chunking
    int n    = swz / 13;
    int cg   = swz % 13;
    int wv   = tid >> 6;
    int lane = tid & 63;
    int cell = cg * 4 + wv;

    const float* r = rois + n * 5;
    int b  = (int)r[0];
    int x1 = (int)(r[1] * SCALE);
    int y1 = (int)(r[2] * SCALE);
    int x2 = (int)(r[3] * SCALE);
    int y2 = (int)(r[4] * SCALE);
    int rh = y2 - y1 + 1;
    int rw = x2 - x1 + 1;

    if (cell < NCELL) {
        int ph = cell / POOLED;
        int pw = cell % POOLED;
        int hs = y1 + (ph * rh) / POOLED;
        int he = y1 + ((ph + 1) * rh + POOLED - 1) / POOLED;
        int ws = x1 + (pw * rw) / POOLED;
        int we = x1 + ((pw + 1) * rw + POOLED - 1) / POOLED;
        int nh = he - hs;
        int nw = we - ws;

        int pos = lane >> 5;       // 0 or 1
        int c8  = lane & 31;       // channel octet

        const f16x8* base = (const f16x8*)(t + (size_t)b * S_ * C_) + c8
                            + (size_t)(hs * W_ + ws) * 32;

        const _Float16 NEGV = (_Float16)(-65504.0f);
        f16x8 a0 = {NEGV, NEGV, NEGV, NEGV, NEGV, NEGV, NEGV, NEGV};
        f16x8 a1 = a0, a2 = a0, a3 = a0;

        for (int h = 0; h < nh; h += 2) {
            int h1 = (h + 1 < nh) ? h + 1 : h;
            const f16x8* hp0 = base + (size_t)h  * (W_ * 32);
            const f16x8* hp1 = base + (size_t)h1 * (W_ * 32);
            for (int w = 0; w < nw; w += 4) {
                int o0 = w + pos;     if (o0 >= nw) o0 = nw - 1;
                int o1 = w + 2 + pos; if (o1 >= nw) o1 = nw - 1;
                a0 = max8h(a0, hp0[(size_t)o0 * 32]);
                a1 = max8h(a1, hp0[(size_t)o1 * 32]);
                a2 = max8h(a2, hp1[(size_t)o0 * 32]);
                a3 = max8h(a3, hp1[(size_t)o1 * 32]);
            }
        }
        f16x8 m = max8h(max8h(a0, a1), max8h(a2, a3));

        union { f16x8 h8; unsigned int uu[4]; } A, B;
        A.h8 = m;
        #pragma unroll
        for (int k = 0; k < 4; ++k) B.uu[k] = __shfl_xor(A.uu[k], 32, 64);
        m = max8h(A.h8, B.h8);

        if (lane < 32) {
            #pragma unroll
            for (int j = 0; j < 8; ++j)
                stage[wv][8 * c8 + j] = (float)m[j];
        }
    }
    __syncthreads();

    float* dst = out + (size_t)n * C_ * NCELL + cg * 4;
    if (cg < 12) {
        #pragma unroll
        for (int k = 0; k < 4; ++k) {
            int f = tid + 256 * k;
            int c = f >> 2, j = f & 3;
            dst[(size_t)c * NCELL + j] = stage[j][c];
        }
    } else {
        dst[(size_t)tid * NCELL] = stage[0][tid];
    }
    __syncthreads();
}

// ---------------- persistent cooperative kernel ----------------
// NOTE: no min-waves arg in launch_bounds — R12's (256,8) capped VGPRs at 32
// and forced scratch spills (VALUBusy 6.7%, 177us). Compiler now free.
__global__ __launch_bounds__(256) void fused_kernel(
    const float* __restrict__ feat, const float* __restrict__ rois,
    _Float16* __restrict__ t, float* __restrict__ out, int nblocks)
{
    __shared__ union {
        float tile[64][65];
        float stage[4][257];
    } sh;
    int tid = threadIdx.x;

    for (int v = blockIdx.x; v < 784; v += nblocks)
        nhwc_tile_body(feat, t, v, tid, sh.tile);

    cgx::this_grid().sync();

    for (int u = blockIdx.x; u < 3328; u += nblocks)
        pool_unit_body(t, rois, out, u, tid, sh.stage);
}

// ---------------- fallback: proven R13 two-kernel path ----------------
__global__ __launch_bounds__(1024) void nhwc_kernel(
    const float* __restrict__ src, _Float16* __restrict__ dst)
{
    __shared__ float tile[64][65];
    int b = blockIdx.z;
    int sbase = blockIdx.x * 64;
    int cbase = blockIdx.y * 64;
    int tid = threadIdx.x;

    const float* s0 = src + (size_t)b * C_ * S_;
    _Float16* d0 = dst + (size_t)b * S_ * C_;

    {
        int si = tid & 15;
        int c  = tid >> 4;
        float4 v = *(const float4*)(s0 + (size_t)(cbase + c) * S_ + sbase + 4 * si);
        tile[4 * si + 0][c] = v.x;
        tile[4 * si + 1][c] = v.y;
        tile[4 * si + 2][c] = v.z;
        tile[4 * si + 3][c] = v.w;
    }
    __syncthreads();
    {
        int cj = tid & 15;
        int s  = tid >> 4;
        f16x4 pk;
        pk[0] = (_Float16)tile[s][4 * cj + 0];
        pk[1] = (_Float16)tile[s][4 * cj + 1];
        pk[2] = (_Float16)tile[s][4 * cj + 2];
        pk[3] = (_Float16)tile[s][4 * cj + 3];
        *(f16x4*)(d0 + (size_t)(sbase + s) * C_ + cbase + 4 * cj) = pk;
    }
}

__global__ __launch_bounds__(256) void pool_fused_kernel(
    const _Float16* __restrict__ t, const float* __restrict__ rois,
    float* __restrict__ out)
{
    __shared__ float stage[4][257];
    pool_unit_body(t, rois, out, blockIdx.x, threadIdx.x, stage);
}

__global__ __launch_bounds__(256) void roipool_direct_kernel(
    const float* __restrict__ feat, const float* __restrict__ rois,
    float* __restrict__ out, int total)
{
    int idx = blockIdx.x * blockDim.x + threadIdx.x;
    if (idx >= total) return;
    int pw = idx % POOLED;
    int ph = (idx / POOLED) % POOLED;
    int c  = (idx / (POOLED * POOLED)) % C_;
    int n  = idx / (POOLED * POOLED * C_);
    const float* r = rois + n * 5;
    int b  = (int)r[0];
    int x1 = (int)(r[1] * SCALE);
    int y1 = (int)(r[2] * SCALE);
    int x2 = (int)(r[3] * SCALE);
    int y2 = (int)(r[4] * SCALE);
    int rh = y2 - y1 + 1;
    int rw = x2 - x1 + 1;
    int hs = y1 + (ph * rh) / POOLED;
    int he = y1 + ((ph + 1) * rh + POOLED - 1) / POOLED;
    int ws = x1 + (pw * rw) / POOLED;
    int we = x1 + ((pw + 1) * rw + POOLED - 1) / POOLED;
    const float* plane = feat + ((size_t)b * C_ + c) * (size_t)S_;
    float m = -INFINITY;
    for (int h = hs; h < he; ++h) {
        const float* row = plane + h * W_;
        for (int w = ws; w < we; ++w) m = fmaxf(m, row[w]);
    }
    out[idx] = m;
}

extern "C" void kernel_launch(void* const* d_in, const int* in_sizes, int n_in,
                              void* d_out, int out_size, void* d_ws, size_t ws_size,
                              hipStream_t stream) {
    const float* feat = (const float*)d_in[0];
    const float* rois = (const float*)d_in[1];
    float* out = (float*)d_out;

    int N = in_sizes[1] / 5;
    size_t featBytes = (size_t)4 * S_ * C_ * sizeof(_Float16);   // 6.4 MB fp16 staging

    if (ws_size >= featBytes && N == 256) {
        _Float16* t = (_Float16*)d_ws;

        int maxB = 0;
        hipError_t qe = hipOccupancyMaxActiveBlocksPerMultiprocessor(
            &maxB, (const void*)fused_kernel, 256, 0);

        if (qe == hipSuccess && maxB > 0) {
            int grid = maxB * 256;
            if (grid > 3328) grid = 3328;
            void* args[] = { (void*)&feat, (void*)&rois, (void*)&t, (void*)&out, (void*)&grid };
            hipError_t le = hipLaunchCooperativeKernel(
                (const void*)fused_kernel, dim3(grid), dim3(256), args, 0, stream);
            if (le == hipSuccess) return;
        }

        dim3 tgrid(S_ / 64, C_ / 64, 4);
        nhwc_kernel<<<tgrid, 1024, 0, stream>>>(feat, t);
        pool_fused_kernel<<<3328, 256, 0, stream>>>(t, rois, out);
    } else {
        int total = N * C_ * POOLED * POOLED;
        roipool_direct_kernel<<<(total + 255) / 256, 256, 0, stream>>>(feat, rois, out, total);
    }
}

// Round 15
// 28.199 us; speedup vs baseline: 3.3152x; 3.3152x over previous
//
#include <hip/hip_runtime.h>
#include <math.h>

#define POOLED 7
#define SCALE 0.0625f
#define C_ 256
#define H_ 56
#define W_ 56
#define S_ (H_ * W_)   // 3136
#define NCELL 49

typedef _Float16 f16x4 __attribute__((ext_vector_type(4)));
typedef _Float16 f16x8 __attribute__((ext_vector_type(8)));

__device__ __forceinline__ f16x8 max8h(f16x8 a, f16x8 b) {
    f16x8 r;
    #pragma unroll
    for (int i = 0; i < 8; ++i) r[i] = a[i] > b[i] ? a[i] : b[i];
    return r;
}

// ---------- Kernel 1: NCHW fp32 -> NHWC fp16 transpose ----------
// grid = (S/64, C/64, B), 1024 threads, 64x64 tile.
__global__ __launch_bounds__(1024) void nhwc_kernel(
    const float* __restrict__ src, _Float16* __restrict__ dst)
{
    __shared__ float tile[64][65];
    int b = blockIdx.z;
    int sbase = blockIdx.x * 64;
    int cbase = blockIdx.y * 64;
    int tid = threadIdx.x;

    const float* s0 = src + (size_t)b * C_ * S_;
    _Float16* d0 = dst + (size_t)b * S_ * C_;

    {
        int si = tid & 15;
        int c  = tid >> 4;
        float4 v = *(const float4*)(s0 + (size_t)(cbase + c) * S_ + sbase + 4 * si);
        tile[4 * si + 0][c] = v.x;
        tile[4 * si + 1][c] = v.y;
        tile[4 * si + 2][c] = v.z;
        tile[4 * si + 3][c] = v.w;
    }
    __syncthreads();
    {
        int cj = tid & 15;
        int s  = tid >> 4;
        f16x4 pk;
        pk[0] = (_Float16)tile[s][4 * cj + 0];
        pk[1] = (_Float16)tile[s][4 * cj + 1];
        pk[2] = (_Float16)tile[s][4 * cj + 2];
        pk[3] = (_Float16)tile[s][4 * cj + 3];
        *(f16x4*)(d0 + (size_t)(sbase + s) * C_ + cbase + 4 * cj) = pk;
    }
}

// ---------- Kernel 2: fused pool + output write, exact load-slot count ----------
// grid = 3328 blocks (256 n x 13 cell-groups), 256 threads = 4 waves.
// Lane l: pos = l>>5, c8 = l&31 (f16x8 = 16B => 2 spatial positions / wave-load).
// Exact pair/tail decomposition removes clamp-duplicate loads (-37% load instrs
// vs R13): full h-pairs, w-tail rem=1/2 -> 1 load, rem=3 -> 2; odd h-tail row
// at half loads.
__global__ __launch_bounds__(256) void pool_fused_kernel(
    const _Float16* __restrict__ t, const float* __restrict__ rois,
    float* __restrict__ out)
{
    __shared__ float stage[4][257];
    int b0   = blockIdx.x;
    int swz  = (b0 & 7) * 416 + (b0 >> 3);   // bijective XCD chunking
    int n    = swz / 13;
    int cg   = swz % 13;
    int wv   = threadIdx.x >> 6;
    int lane = threadIdx.x & 63;
    int cell = cg * 4 + wv;

    const float* r = rois + n * 5;
    int b  = (int)r[0];
    int x1 = (int)(r[1] * SCALE);
    int y1 = (int)(r[2] * SCALE);
    int x2 = (int)(r[3] * SCALE);
    int y2 = (int)(r[4] * SCALE);
    int rh = y2 - y1 + 1;
    int rw = x2 - x1 + 1;

    if (cell < NCELL) {
        int ph = cell / POOLED;
        int pw = cell % POOLED;
        int hs = y1 + (ph * rh) / POOLED;
        int he = y1 + ((ph + 1) * rh + POOLED - 1) / POOLED;
        int ws = x1 + (pw * rw) / POOLED;
        int we = x1 + ((pw + 1) * rw + POOLED - 1) / POOLED;
        int nh = he - hs;
        int nw = we - ws;

        int pos = lane >> 5;       // 0 or 1
        int c8  = lane & 31;       // channel octet

        const f16x8* base = (const f16x8*)(t + (size_t)b * S_ * C_) + c8
                            + (size_t)(hs * W_ + ws) * 32;

        const _Float16 NEGV = (_Float16)(-65504.0f);
        f16x8 a0 = {NEGV, NEGV, NEGV, NEGV, NEGV, NEGV, NEGV, NEGV};
        f16x8 a1 = a0, a2 = a0, a3 = a0;

        int h = 0;
        for (; h + 1 < nh; h += 2) {
            const f16x8* hp0 = base + (size_t)h * (W_ * 32);
            const f16x8* hp1 = hp0 + (W_ * 32);
            int w = 0;
            for (; w + 4 <= nw; w += 4) {
                a0 = max8h(a0, hp0[(size_t)(w + pos) * 32]);
                a1 = max8h(a1, hp0[(size_t)(w + 2 + pos) * 32]);
                a2 = max8h(a2, hp1[(size_t)(w + pos) * 32]);
                a3 = max8h(a3, hp1[(size_t)(w + 2 + pos) * 32]);
            }
            int rem = nw - w;                     // 0..3
            if (rem > 0) {
                int o0 = w + (pos < rem ? pos : rem - 1);
                a0 = max8h(a0, hp0[(size_t)o0 * 32]);
                a2 = max8h(a2, hp1[(size_t)o0 * 32]);
                if (rem == 3) {
                    a1 = max8h(a1, hp0[(size_t)(w + 2) * 32]);
                    a3 = max8h(a3, hp1[(size_t)(w + 2) * 32]);
                }
            }
        }
        if (h < nh) {                             // odd tail row
            const f16x8* hp0 = base + (size_t)h * (W_ * 32);
            int w = 0;
            for (; w + 4 <= nw; w += 4) {
                a0 = max8h(a0, hp0[(size_t)(w + pos) * 32]);
                a1 = max8h(a1, hp0[(size_t)(w + 2 + pos) * 32]);
            }
            int rem = nw - w;
            if (rem > 0) {
                int o0 = w + (pos < rem ? pos : rem - 1);
                a0 = max8h(a0, hp0[(size_t)o0 * 32]);
                if (rem == 3) a1 = max8h(a1, hp0[(size_t)(w + 2) * 32]);
            }
        }
        f16x8 m = max8h(max8h(a0, a1), max8h(a2, a3));

        // combine the two position-halves of the wave
        union { f16x8 h8; unsigned int uu[4]; } A, B;
        A.h8 = m;
        #pragma unroll
        for (int k = 0; k < 4; ++k) B.uu[k] = __shfl_xor(A.uu[k], 32, 64);
        m = max8h(A.h8, B.h8);

        if (lane < 32) {
            #pragma unroll
            for (int j = 0; j < 8; ++j)
                stage[wv][8 * c8 + j] = (float)m[j];
        }
    }
    __syncthreads();

    float* dst = out + (size_t)n * C_ * NCELL + cg * 4;
    if (cg < 12) {
        #pragma unroll
        for (int k = 0; k < 4; ++k) {
            int f = threadIdx.x + 256 * k;
            int c = f >> 2, j = f & 3;
            dst[(size_t)c * NCELL + j] = stage[j][c];
        }
    } else {
        dst[(size_t)threadIdx.x * NCELL] = stage[0][threadIdx.x];
    }
}

// ---------- Fallback if workspace too small ----------
__global__ __launch_bounds__(256) void roipool_direct_kernel(
    const float* __restrict__ feat, const float* __restrict__ rois,
    float* __restrict__ out, int total)
{
    int idx = blockIdx.x * blockDim.x + threadIdx.x;
    if (idx >= total) return;
    int pw = idx % POOLED;
    int ph = (idx / POOLED) % POOLED;
    int c  = (idx / (POOLED * POOLED)) % C_;
    int n  = idx / (POOLED * POOLED * C_);
    const float* r = rois + n * 5;
    int b  = (int)r[0];
    int x1 = (int)(r[1] * SCALE);
    int y1 = (int)(r[2] * SCALE);
    int x2 = (int)(r[3] * SCALE);
    int y2 = (int)(r[4] * SCALE);
    int rh = y2 - y1 + 1;
    int rw = x2 - x1 + 1;
    int hs = y1 + (ph * rh) / POOLED;
    int he = y1 + ((ph + 1) * rh + POOLED - 1) / POOLED;
    int ws = x1 + (pw * rw) / POOLED;
    int we = x1 + ((pw + 1) * rw + POOLED - 1) / POOLED;
    const float* plane = feat + ((size_t)b * C_ + c) * (size_t)S_;
    float m = -INFINITY;
    for (int h = hs; h < he; ++h) {
        const float* row = plane + h * W_;
        for (int w = ws; w < we; ++w) m = fmaxf(m, row[w]);
    }
    out[idx] = m;
}

extern "C" void kernel_launch(void* const* d_in, const int* in_sizes, int n_in,
                              void* d_out, int out_size, void* d_ws, size_t ws_size,
                              hipStream_t stream) {
    const float* feat = (const float*)d_in[0];
    const float* rois = (const float*)d_in[1];
    float* out = (float*)d_out;

    int N = in_sizes[1] / 5;
    size_t featBytes = (size_t)4 * S_ * C_ * sizeof(_Float16);   // 6.4 MB fp16 staging

    if (ws_size >= featBytes && N == 256) {
        _Float16* t = (_Float16*)d_ws;

        dim3 tgrid(S_ / 64, C_ / 64, 4);
        nhwc_kernel<<<tgrid, 1024, 0, stream>>>(feat, t);

        pool_fused_kernel<<<3328, 256, 0, stream>>>(t, rois, out);
    } else {
        int total = N * C_ * POOLED * POOLED;
        roipool_direct_kernel<<<(total + 255) / 256, 256, 0, stream>>>(feat, rois, out, total);
    }
}